// Round 15
// baseline (323.157 us; speedup 1.0000x reference)
//
#include <hip/hip_runtime.h>
#include <hip/hip_bf16.h>

#define NB  32
#define NTQ 1024
#define NTV 1024
#define ND  512

typedef float f32x4 __attribute__((ext_vector_type(4)));
typedef float f32x2 __attribute__((ext_vector_type(2)));
typedef __bf16 bf16x8 __attribute__((ext_vector_type(8)));
typedef _Float16 f16x8 __attribute__((ext_vector_type(8)));
typedef unsigned short u16x4 __attribute__((ext_vector_type(4)));
typedef unsigned short u16x8 __attribute__((ext_vector_type(8)));
typedef unsigned int u32x2 __attribute__((ext_vector_type(2)));
typedef unsigned int u32x4 __attribute__((ext_vector_type(4)));

static __device__ __forceinline__ unsigned short f2h(float x) {   // f32 -> fp16 (RTN)
  _Float16 h = (_Float16)x;
  return __builtin_bit_cast(unsigned short, h);
}
static __device__ __forceinline__ float h2f(unsigned short u) {
  return (float)__builtin_bit_cast(_Float16, u);
}
// trunc split for bf16 hi/lo: packed (hi | lo<<16)
static __device__ __forceinline__ unsigned split2(float x) {
  unsigned u = __builtin_bit_cast(unsigned, x);
  unsigned h = u >> 16;
  float hf = __builtin_bit_cast(float, u & 0xffff0000u);
  unsigned l = __builtin_bit_cast(unsigned, x - hf) >> 16;
  return h | (l << 16);
}
static __device__ __forceinline__ f32x4 mfma_bf(bf16x8 a, bf16x8 b, f32x4 c) {
  return __builtin_amdgcn_mfma_f32_16x16x32_bf16(a, b, c, 0, 0, 0);
}
static __device__ __forceinline__ f32x4 mfma_h(f16x8 a, f16x8 b, f32x4 c) {
  return __builtin_amdgcn_mfma_f32_16x16x32_f16(a, b, c, 0, 0, 0);
}
// async 16B global -> LDS (lds dest wave-uniform base; HW adds lane*16)
static __device__ __forceinline__ void gload16(const unsigned short* g, unsigned short* l) {
  __builtin_amdgcn_global_load_lds((const __attribute__((address_space(1))) unsigned*)g,
                                   (__attribute__((address_space(3))) unsigned*)l, 16, 0, 0);
}

// ---- kernel 0: fused prep — V->Vt fp16 transpose (bid<4096) | Q->fp16 plane (bid>=4096) ----
__global__ __launch_bounds__(256) void k_prep(const float* __restrict__ V,
                                              const float* __restrict__ Q,
                                              unsigned short* __restrict__ Vt,
                                              unsigned short* __restrict__ qh) {
  __shared__ unsigned short L[64][72];
  int bid = blockIdx.x, t = threadIdx.x;
  if (bid < 4096) {                       // V [B,TV,D] -> Vt [B,D,TV] fp16
    int vt = bid & 15, dt = (bid >> 4) & 7, b = bid >> 7;
#pragma unroll
    for (int r = 0; r < 4; ++r) {
      int v = (t >> 4) + r * 16;
      int c4 = (t & 15) * 4;
      f32x4 x = *(const f32x4*)(V + (size_t)(b * NTV + vt * 64 + v) * ND + dt * 64 + c4);
      u16x4 h;
#pragma unroll
      for (int j = 0; j < 4; ++j) h[j] = f2h(x[j]);
      *(u16x4*)&L[v][c4] = h;
    }
    __syncthreads();
#pragma unroll
    for (int r = 0; r < 4; ++r) {
      int d = (t >> 4) + r * 16;
      int v4 = (t & 15) * 4;
      u16x4 o;
#pragma unroll
      for (int i = 0; i < 4; ++i) o[i] = L[v4 + i][d];
      *(u16x4*)(Vt + (size_t)(b * ND + dt * 64 + d) * NTV + vt * 64 + v4) = o;
    }
  } else {                                // Q f32 -> fp16 plane
    int base = (bid - 4096) * 1024 + t;
#pragma unroll
    for (int k = 0; k < 4; ++k) {
      size_t c = (size_t)(base + k * 256) * 4;
      f32x4 x = *(const f32x4*)(Q + c);
      u16x4 h;
#pragma unroll
      for (int j = 0; j < 4; ++j) h[j] = f2h(x[j]);
      *(u16x4*)(qh + c) = h;
    }
  }
}

// ------- kernel 1: keys = V @ W^T + bias; split-bf16 3-MFMA core; fp16-plane output -------
__global__ __launch_bounds__(256, 2) void k_keys(const float* __restrict__ V,
                                                 const float* __restrict__ W,
                                                 const float* __restrict__ bias,
                                                 unsigned short* __restrict__ kp) {
  int bid = blockIdx.x;
  int swz = (bid & 7) * 128 + (bid >> 3);
  int bm = swz >> 2, bn = swz & 3;
  int t = threadIdx.x, lane = t & 63, w = t >> 6;
  int l15 = lane & 15, g = lane >> 4;
  int wr = (w >> 1) * 64, wc = (w & 1) * 64;
  __shared__ __align__(16) unsigned char SMEM[73728];
  auto Ah = (unsigned short(*)[72])(SMEM);
  auto Al = (unsigned short(*)[72])(SMEM + 18432);
  auto Bh = (unsigned short(*)[72])(SMEM + 36864);
  auto Bl = (unsigned short(*)[72])(SMEM + 55296);
  f32x4 acc[4][4] = {};
  const int row0 = bm * 128, col0 = bn * 128;
  int srow = t >> 4, c4 = (t & 15) * 4;

  f32x4 vreg[8], wreg[8];
#pragma unroll
  for (int r = 0; r < 8; ++r) {
    vreg[r] = *(const f32x4*)(V + (size_t)(row0 + srow + r * 16) * ND + c4);
    wreg[r] = *(const f32x4*)(W + (size_t)(col0 + srow + r * 16) * ND + c4);
  }
  for (int k0 = 0; k0 < ND; k0 += 64) {
    __syncthreads();
#pragma unroll
    for (int r = 0; r < 8; ++r) {
      int row = srow + r * 16;
      u16x4 h, l;
#pragma unroll
      for (int j = 0; j < 4; ++j) {
        unsigned p = split2(vreg[r][j]);
        h[j] = (unsigned short)(p & 0xffffu); l[j] = (unsigned short)(p >> 16);
      }
      *(u16x4*)&Ah[row][c4] = h; *(u16x4*)&Al[row][c4] = l;
#pragma unroll
      for (int j = 0; j < 4; ++j) {
        unsigned p = split2(wreg[r][j]);
        h[j] = (unsigned short)(p & 0xffffu); l[j] = (unsigned short)(p >> 16);
      }
      *(u16x4*)&Bh[row][c4] = h; *(u16x4*)&Bl[row][c4] = l;
    }
    __syncthreads();
    if (k0 + 64 < ND) {
#pragma unroll
      for (int r = 0; r < 8; ++r) {
        vreg[r] = *(const f32x4*)(V + (size_t)(row0 + srow + r * 16) * ND + k0 + 64 + c4);
        wreg[r] = *(const f32x4*)(W + (size_t)(col0 + srow + r * 16) * ND + k0 + 64 + c4);
      }
    }
#pragma unroll
    for (int kk = 0; kk < 2; ++kk) {
      int kof = kk * 32 + g * 8;
      bf16x8 ah[4], al[4], bh[4], bl[4];
#pragma unroll
      for (int i = 0; i < 4; ++i) {
        int ra = wr + i * 16 + l15;
        ah[i] = *(const bf16x8*)&Ah[ra][kof];
        al[i] = *(const bf16x8*)&Al[ra][kof];
        int rb = wc + i * 16 + l15;
        bh[i] = *(const bf16x8*)&Bh[rb][kof];
        bl[i] = *(const bf16x8*)&Bl[rb][kof];
      }
#pragma unroll
      for (int i = 0; i < 4; ++i)
#pragma unroll
        for (int j = 0; j < 4; ++j) {
          acc[i][j] = mfma_bf(ah[i], bh[j], acc[i][j]);
          acc[i][j] = mfma_bf(ah[i], bl[j], acc[i][j]);
          acc[i][j] = mfma_bf(al[i], bh[j], acc[i][j]);
        }
    }
  }
  // epilogue: f32 C-tile in LDS (pitch 132), then fp16 coalesced writes (256B runs)
  __syncthreads();
  float* CT = (float*)SMEM;                    // 128 x 132 f32 = 67584 B
#pragma unroll
  for (int j = 0; j < 4; ++j) {
    int col_l = wc + j * 16 + l15;
    float bj = bias[col0 + col_l];
#pragma unroll
    for (int i = 0; i < 4; ++i) {
      int rb_l = wr + i * 16 + g * 4;
#pragma unroll
      for (int r = 0; r < 4; ++r) CT[(rb_l + r) * 132 + col_l] = acc[i][j][r] + bj;
    }
  }
  __syncthreads();
#pragma unroll
  for (int it = 0; it < 16; ++it) {
    int idx = it * 256 + t;                  // 4096 chunks of 4
    int row = idx >> 5, cc = (idx & 31) * 4;
    f32x4 x = *(const f32x4*)&CT[row * 132 + cc];
    u16x4 h;
#pragma unroll
    for (int j = 0; j < 4; ++j) h[j] = f2h(x[j]);
    *(u16x4*)(kp + (size_t)(row0 + row) * 2048 + col0 + cc) = h;
  }
}

// ------- kernel 2: scores = Q @ keys^T in fp16 single-MFMA via global_load_lds + swizzle -------
// + fused block softmax: e = exp(s - m_blk) fp16 [b][q][v] -> ebase; partial (m,l).
__global__ __launch_bounds__(256, 4) void k_scores(const unsigned short* __restrict__ qh,
                                                   const unsigned short* kp,
                                                   unsigned short* ebase,
                                                   float2* __restrict__ partials) {
  int bid = blockIdx.x;
  int swz = (bid & 7) * 256 + (bid >> 3);
  int b = swz >> 6, rr2 = swz & 63, vt = rr2 >> 3, qt = rr2 & 7;
  int t = threadIdx.x, lane = t & 63, w = t >> 6, g = lane >> 4, l15 = lane & 15;
  int wr = (w >> 1) * 64, wc = (w & 1) * 64;
  __shared__ __align__(16) unsigned char SMEM[36864];
  unsigned short* lds = (unsigned short*)SMEM;   // A @ u16 0, B @ u16 8192
  f32x4 acc[4][4] = {};
  const size_t qrow = (size_t)(b * NTQ + qt * 128);
  const size_t krow = (size_t)(b * NTV + vt * 128);
  int grow = lane >> 3;          // row sub-index within chunk
  int gcg = lane & 7;            // col granule (16B) within 128B row

  for (int k0 = 0; k0 < ND; k0 += 64) {
    __syncthreads();
#pragma unroll
    for (int i = 0; i < 4; ++i) {
      int c = i * 4 + w;                       // 0..15
      int row = c * 8 + grow;                  // 0..127
      int scg = gcg ^ (row & 7);               // inverse-swizzled SOURCE column-group
      gload16(qh + (qrow + row) * 512 + k0 + scg * 8, lds + c * 512);
      gload16(kp + (krow + row) * 2048 + k0 + scg * 8, lds + 8192 + c * 512);
    }
    __syncthreads();                           // drains vmcnt -> tiles ready
#pragma unroll
    for (int kk = 0; kk < 2; ++kk) {
      f16x8 af[4], bfr[4];
#pragma unroll
      for (int i = 0; i < 4; ++i) {
        int ra = wr + i * 16 + l15;
        int go = ((kk * 4 + g) ^ (ra & 7)) * 8;   // swizzled read column offset (u16)
        af[i] = *(const f16x8*)(lds + ra * 64 + go);
        int rb = wc + i * 16 + l15;
        int go2 = ((kk * 4 + g) ^ (rb & 7)) * 8;
        bfr[i] = *(const f16x8*)(lds + 8192 + rb * 64 + go2);
      }
#pragma unroll
      for (int i = 0; i < 4; ++i)
#pragma unroll
        for (int j = 0; j < 4; ++j) acc[i][j] = mfma_h(af[i], bfr[j], acc[i][j]);
    }
  }
  // ---- fused block softmax: m over this block's 128 v per q; e tile fp16 [q][v]; partial (m,l) ----
  __syncthreads();
  auto E2 = (unsigned short(*)[136])(SMEM);     // [128 q][136] u16 = 34816 B
  float* Lm = (float*)(SMEM + 34816);           // [128][2] f32
  float* Ls = (float*)(SMEM + 35840);
#pragma unroll
  for (int i = 0; i < 4; ++i)
#pragma unroll
    for (int r = 0; r < 4; ++r) {
      float m = fmaxf(fmaxf(acc[i][0][r], acc[i][1][r]), fmaxf(acc[i][2][r], acc[i][3][r]));
#pragma unroll
      for (int msk = 1; msk < 16; msk <<= 1) m = fmaxf(m, __shfl_xor(m, msk));
      if (l15 == 0) Lm[(wr + i * 16 + g * 4 + r) * 2 + (w & 1)] = m;
    }
  __syncthreads();
#pragma unroll
  for (int i = 0; i < 4; ++i)
#pragma unroll
    for (int r = 0; r < 4; ++r) {
      int ql = wr + i * 16 + g * 4 + r;
      float mf = fmaxf(Lm[ql * 2], Lm[ql * 2 + 1]);
      float s = 0.f;
#pragma unroll
      for (int j = 0; j < 4; ++j) {
        float e = __expf(acc[i][j][r] - mf);
        s += e;
        E2[ql][wc + j * 16 + l15] = f2h(e);     // q-major store
      }
#pragma unroll
      for (int msk = 1; msk < 16; msk <<= 1) s += __shfl_xor(s, msk);
      if (l15 == 0) Ls[ql * 2 + (w & 1)] = s;
    }
  __syncthreads();
  if (t < 128) {
    float mf = fmaxf(Lm[t * 2], Lm[t * 2 + 1]);
    float lf = Ls[t * 2] + Ls[t * 2 + 1];
    partials[(((size_t)(b * 8 + vt)) << 10) + qt * 128 + t] = make_float2(mf, lf);
  }
  // e rows q (128), 256B runs at v-column offset vt*128
#pragma unroll
  for (int it = 0; it < 8; ++it) {
    int idx = it * 256 + t;
    int row = idx >> 4, ch = idx & 15;
    *(u16x8*)(ebase + (size_t)(b * 1024 + qt * 128 + row) * 2048 + 1024 + vt * 128 + ch * 8) =
        *(const u16x8*)&E2[row][ch * 8];
  }
}

// ------- kernel 3: combine 8 partials per (b,q) -> global (M, 1/L) -------
__global__ __launch_bounds__(256) void k_combine(const float2* __restrict__ partials,
                                                 float2* __restrict__ stats) {
  int idx = blockIdx.x * 256 + threadIdx.x;   // 32768
  int b = idx >> 10, q = idx & 1023;
  float2 p[8];
  float M = -3.0e38f;
#pragma unroll
  for (int vt = 0; vt < 8; ++vt) {
    p[vt] = partials[(((size_t)(b * 8 + vt)) << 10) + q];
    M = fmaxf(M, p[vt].x);
  }
  float L = 0.f;
#pragma unroll
  for (int vt = 0; vt < 8; ++vt) L += p[vt].y * __expf(p[vt].x - M);
  stats[idx] = make_float2(M, 1.0f / L);
}

// ------- kernel 4: context = alpha @ V ; 128q x 128d fp16 tile GEMM over K=v -------
__global__ __launch_bounds__(256, 4) void k_pv(const unsigned short* __restrict__ ebase,
                                               const unsigned short* __restrict__ Vt,
                                               const float2* __restrict__ stats,
                                               const float2* __restrict__ partials,
                                               float* __restrict__ out1) {
  int bid = blockIdx.x;
  int swz = (bid & 7) * 128 + (bid >> 3);
  int b = swz >> 5, qt = (swz >> 2) & 7, dt = swz & 3;
  int t = threadIdx.x, lane = t & 63, w = t >> 6;
  int l15 = lane & 15, g = lane >> 4;
  int wr = (w >> 1) * 64, wc = (w & 1) * 64;
  int q0 = qt * 128, d0 = dt * 128;
  __shared__ __align__(16) unsigned char SMEM[36864];
  auto Ae = (unsigned short(*)[72])(SMEM);           // [128 q][72]
  auto Bv = (unsigned short(*)[72])(SMEM + 18432);   // [128 d][72]
  f32x4 acc[4][4] = {};

  int srow = t >> 3, c8 = (t & 7) * 8;
  float M4[4], iL4[4];
#pragma unroll
  for (int k = 0; k < 4; ++k) {
    float2 st = stats[b * NTQ + q0 + srow + 32 * k];
    M4[k] = st.x; iL4[k] = st.y;
  }
  u16x8 ereg[4], vreg[4];
#pragma unroll
  for (int k = 0; k < 4; ++k) {
    ereg[k] = *(const u16x8*)(ebase + (size_t)(b * 1024 + q0 + srow + 32 * k) * 2048 + 1024 + c8);
    vreg[k] = *(const u16x8*)(Vt + ((size_t)b * ND + d0 + srow + 32 * k) * NTV + c8);
  }
  float sck[4];
  for (int v0 = 0; v0 < NTV; v0 += 64) {
    if ((v0 & 127) == 0) {
      int vt128 = v0 >> 7;
#pragma unroll
      for (int k = 0; k < 4; ++k) {
        float2 p = partials[(((size_t)(b * 8 + vt128)) << 10) + q0 + srow + 32 * k];
        sck[k] = __expf(p.x - M4[k]) * iL4[k];
      }
    }
    __syncthreads();
#pragma unroll
    for (int k = 0; k < 4; ++k) {
      int row = srow + 32 * k;
      u16x8 a;
#pragma unroll
      for (int m = 0; m < 8; ++m) a[m] = f2h(h2f(ereg[k][m]) * sck[k]);
      *(u16x8*)&Ae[row][c8] = a;
      *(u16x8*)&Bv[row][c8] = vreg[k];
    }
    if (v0 + 64 < NTV) {
#pragma unroll
      for (int k = 0; k < 4; ++k) {
        ereg[k] = *(const u16x8*)(ebase + (size_t)(b * 1024 + q0 + srow + 32 * k) * 2048 + 1024 + v0 + 64 + c8);
        vreg[k] = *(const u16x8*)(Vt + ((size_t)b * ND + d0 + srow + 32 * k) * NTV + v0 + 64 + c8);
      }
    }
    __syncthreads();
#pragma unroll
    for (int kk = 0; kk < 2; ++kk) {
      int kof = kk * 32 + g * 8;
      f16x8 af[4], bfr[4];
#pragma unroll
      for (int i = 0; i < 4; ++i) af[i] = *(const f16x8*)&Ae[wr + i * 16 + l15][kof];
#pragma unroll
      for (int j = 0; j < 4; ++j) bfr[j] = *(const f16x8*)&Bv[wc + j * 16 + l15][kof];
#pragma unroll
      for (int i = 0; i < 4; ++i)
#pragma unroll
        for (int j = 0; j < 4; ++j) acc[i][j] = mfma_h(af[i], bfr[j], acc[i][j]);
    }
  }
  float* CT = (float*)SMEM;
#pragma unroll
  for (int h = 0; h < 2; ++h) {
    __syncthreads();
    if ((w >> 1) == h) {
#pragma unroll
      for (int i = 0; i < 4; ++i)
#pragma unroll
        for (int j = 0; j < 4; ++j) {
          int ql = i * 16 + g * 4;
          int dl = wc + j * 16 + l15;
#pragma unroll
          for (int r = 0; r < 4; ++r) CT[(ql + r) * 132 + dl] = acc[i][j][r];
        }
    }
    __syncthreads();
#pragma unroll
    for (int it = 0; it < 8; ++it) {
      int idx = it * 256 + t;
      int row = idx >> 5, c4 = idx & 31;
      *(f32x4*)(out1 + (size_t)(b * NTQ + q0 + h * 64 + row) * 1024 + d0 + c4 * 4) =
          *(const f32x4*)&CT[row * 132 + c4 * 4];
    }
  }
}

// ------- kernel 5: alpha = e*sc -> out2 (via swizzled LDS transpose) + fused Q-concat -------
__global__ __launch_bounds__(256) void k_alpha(const unsigned short* ebase,
                                               const float* __restrict__ Q,
                                               const float2* __restrict__ stats,
                                               const float2* __restrict__ partials,
                                               float* out2,
                                               float* out1) {
  int bid = blockIdx.x;                       // 512
  int swz = (bid & 7) * 64 + (bid >> 3);
  int b = swz >> 4, qc = swz & 15;
  int q0 = qc * 64;
  int t = threadIdx.x;
  __shared__ float T[128][68];
  int row = t >> 4, ch = t & 15;
  float M4[4], iL4[4];
#pragma unroll
  for (int k = 0; k < 4; ++k) {
    float2 st = stats[b * NTQ + q0 + row + 16 * k];
    M4[k] = st.x; iL4[k] = st.y;
  }
  for (int vt = 0; vt < 8; ++vt) {
    __syncthreads();
#pragma unroll
    for (int k = 0; k < 4; ++k) {
      int r = row + 16 * k;
      float2 p = partials[(((size_t)(b * 8 + vt)) << 10) + q0 + r];
      float sc = __expf(p.x - M4[k]) * iL4[k];
      u16x8 ev = *(const u16x8*)(ebase + (size_t)(b * 1024 + q0 + r) * 2048 + 1024 + vt * 128 + ch * 8);
#pragma unroll
      for (int m = 0; m < 8; ++m) {
        int v = ch * 8 + m;
        T[v][r ^ (((v >> 3) & 7) << 3)] = h2f(ev[m]) * sc;
      }
    }
    __syncthreads();
#pragma unroll
    for (int it = 0; it < 8; ++it) {
      int idx = it * 256 + t;
      int vr = idx >> 4, c4 = idx & 15;
      int cs = (c4 * 4) ^ (((vr >> 3) & 7) << 3);
      *(f32x4*)(out2 + ((size_t)(b * 1024) + vt * 128 + vr) * 1024 + q0 + c4 * 4) =
          *(const f32x4*)&T[vr][cs];
    }
  }
  __syncthreads();
#pragma unroll
  for (int k = 0; k < 32; ++k) {
    int idx = k * 256 + t;
    int r = idx >> 7, c4 = idx & 127;
    *(f32x4*)(out1 + (size_t)(b * 1024 + q0 + r) * 1024 + 512 + c4 * 4) =
        *(const f32x4*)(Q + (size_t)(b * 1024 + q0 + r) * 512 + c4 * 4);
  }
}

extern "C" void kernel_launch(void* const* d_in, const int* in_sizes, int n_in,
                              void* d_out, int out_size, void* d_ws, size_t ws_size,
                              hipStream_t stream) {
  const float* Q    = (const float*)d_in[0];
  const float* V    = (const float*)d_in[1];
  const float* W    = (const float*)d_in[2];
  const float* bias = (const float*)d_in[3];

  float* out1 = (float*)d_out;                                   // context_cat [B,TQ,2D]
  float* out2 = (float*)d_out + (size_t)NB * NTQ * (2 * ND);     // alignment_t [B,TV,TQ]

  unsigned short* Vt = (unsigned short*)d_ws;                    // fp16 [B,D,TV]  32MB
  float2* stats    = (float2*)((char*)d_ws + 33554432);          // 256KB
  float2* partials = (float2*)((char*)d_ws + 33554432 + 262144); // 2MB

  // keys fp16 plane: out1 row (b,v) u16 [0..511]
  unsigned short* kp = (unsigned short*)out1;
  // e fp16 [b][q][v]: out1 row (b,q) u16 [1024..2047]
  unsigned short* ebase = (unsigned short*)out1;
  // q fp16 plane: out2 region start (dead until k_alpha)
  unsigned short* qh = (unsigned short*)out2;

  k_prep<<<8192, 256, 0, stream>>>(V, Q, Vt, qh);
  k_keys<<<1024, 256, 0, stream>>>(V, W, bias, kp);
  k_scores<<<2048, 256, 0, stream>>>(qh, kp, ebase, partials);
  k_combine<<<128, 256, 0, stream>>>(partials, stats);
  k_pv<<<1024, 256, 0, stream>>>(ebase, Vt, stats, partials, out1);
  k_alpha<<<512, 256, 0, stream>>>(ebase, Q, stats, partials, out2, out1);
}

// Round 16
// 275.495 us; speedup vs baseline: 1.1730x; 1.1730x over previous
//
#include <hip/hip_runtime.h>
#include <hip/hip_bf16.h>

#define NB  32
#define NTQ 1024
#define NTV 1024
#define ND  512

typedef float f32x4 __attribute__((ext_vector_type(4)));
typedef float f32x2 __attribute__((ext_vector_type(2)));
typedef __bf16 bf16x8 __attribute__((ext_vector_type(8)));
typedef _Float16 f16x8 __attribute__((ext_vector_type(8)));
typedef unsigned short u16x4 __attribute__((ext_vector_type(4)));
typedef unsigned short u16x8 __attribute__((ext_vector_type(8)));
typedef unsigned int u32x2 __attribute__((ext_vector_type(2)));
typedef unsigned int u32x4 __attribute__((ext_vector_type(4)));

static __device__ __forceinline__ unsigned short f2h(float x) {   // f32 -> fp16 (RTN)
  _Float16 h = (_Float16)x;
  return __builtin_bit_cast(unsigned short, h);
}
static __device__ __forceinline__ float h2f(unsigned short u) {
  return (float)__builtin_bit_cast(_Float16, u);
}
// trunc split for bf16 hi/lo: packed (hi | lo<<16)
static __device__ __forceinline__ unsigned split2(float x) {
  unsigned u = __builtin_bit_cast(unsigned, x);
  unsigned h = u >> 16;
  float hf = __builtin_bit_cast(float, u & 0xffff0000u);
  unsigned l = __builtin_bit_cast(unsigned, x - hf) >> 16;
  return h | (l << 16);
}
static __device__ __forceinline__ f32x4 mfma_bf(bf16x8 a, bf16x8 b, f32x4 c) {
  return __builtin_amdgcn_mfma_f32_16x16x32_bf16(a, b, c, 0, 0, 0);
}
static __device__ __forceinline__ f32x4 mfma_h(f16x8 a, f16x8 b, f32x4 c) {
  return __builtin_amdgcn_mfma_f32_16x16x32_f16(a, b, c, 0, 0, 0);
}
// async 16B global -> LDS (lds dest wave-uniform base; HW adds lane*16)
static __device__ __forceinline__ void gload16(const unsigned short* g, unsigned short* l) {
  __builtin_amdgcn_global_load_lds((const __attribute__((address_space(1))) unsigned*)g,
                                   (__attribute__((address_space(3))) unsigned*)l, 16, 0, 0);
}

// ---------------- kernel 0: V [B,TV,D] f32 -> Vt [B,D,TV] fp16 ----------------
__global__ __launch_bounds__(256) void k_vt(const float* __restrict__ V,
                                            unsigned short* __restrict__ Vt) {
  int vt = blockIdx.x, dt = blockIdx.y, b = blockIdx.z;
  int t = threadIdx.x;
  __shared__ unsigned short L[64][72];
#pragma unroll
  for (int r = 0; r < 4; ++r) {
    int v = (t >> 4) + r * 16;
    int c4 = (t & 15) * 4;
    f32x4 x = *(const f32x4*)(V + (size_t)(b * NTV + vt * 64 + v) * ND + dt * 64 + c4);
    u16x4 h;
#pragma unroll
    for (int j = 0; j < 4; ++j) h[j] = f2h(x[j]);
    *(u16x4*)&L[v][c4] = h;
  }
  __syncthreads();
#pragma unroll
  for (int r = 0; r < 4; ++r) {
    int d = (t >> 4) + r * 16;
    int v4 = (t & 15) * 4;
    u16x4 o;
#pragma unroll
    for (int i = 0; i < 4; ++i) o[i] = L[v4 + i][d];
    *(u16x4*)(Vt + (size_t)(b * ND + dt * 64 + d) * NTV + vt * 64 + v4) = o;
  }
}

// ---------------- kernel 0b: Q f32 -> fp16 plane [32768 rows][512] ----------------
__global__ __launch_bounds__(256) void k_qhalf(const float* __restrict__ Q,
                                               unsigned short* __restrict__ qh) {
  int base = blockIdx.x * 1024 + threadIdx.x;
#pragma unroll
  for (int k = 0; k < 4; ++k) {
    size_t c = (size_t)(base + k * 256) * 4;   // 4,194,304 chunks of 4
    f32x4 x = *(const f32x4*)(Q + c);
    u16x4 h;
#pragma unroll
    for (int j = 0; j < 4; ++j) h[j] = f2h(x[j]);
    *(u16x4*)(qh + c) = h;
  }
}

// ------- kernel 1: keys = V @ W^T + bias; split-bf16 3-MFMA core; fp16-plane output -------
__global__ __launch_bounds__(256, 2) void k_keys(const float* __restrict__ V,
                                                 const float* __restrict__ W,
                                                 const float* __restrict__ bias,
                                                 unsigned short* __restrict__ kp) {
  int bid = blockIdx.x;
  int swz = (bid & 7) * 128 + (bid >> 3);
  int bm = swz >> 2, bn = swz & 3;
  int t = threadIdx.x, lane = t & 63, w = t >> 6;
  int l15 = lane & 15, g = lane >> 4;
  int wr = (w >> 1) * 64, wc = (w & 1) * 64;
  __shared__ __align__(16) unsigned char SMEM[73728];
  auto Ah = (unsigned short(*)[72])(SMEM);
  auto Al = (unsigned short(*)[72])(SMEM + 18432);
  auto Bh = (unsigned short(*)[72])(SMEM + 36864);
  auto Bl = (unsigned short(*)[72])(SMEM + 55296);
  f32x4 acc[4][4] = {};
  const int row0 = bm * 128, col0 = bn * 128;
  int srow = t >> 4, c4 = (t & 15) * 4;

  f32x4 vreg[8], wreg[8];
#pragma unroll
  for (int r = 0; r < 8; ++r) {
    vreg[r] = *(const f32x4*)(V + (size_t)(row0 + srow + r * 16) * ND + c4);
    wreg[r] = *(const f32x4*)(W + (size_t)(col0 + srow + r * 16) * ND + c4);
  }
  for (int k0 = 0; k0 < ND; k0 += 64) {
    __syncthreads();
#pragma unroll
    for (int r = 0; r < 8; ++r) {
      int row = srow + r * 16;
      u16x4 h, l;
#pragma unroll
      for (int j = 0; j < 4; ++j) {
        unsigned p = split2(vreg[r][j]);
        h[j] = (unsigned short)(p & 0xffffu); l[j] = (unsigned short)(p >> 16);
      }
      *(u16x4*)&Ah[row][c4] = h; *(u16x4*)&Al[row][c4] = l;
#pragma unroll
      for (int j = 0; j < 4; ++j) {
        unsigned p = split2(wreg[r][j]);
        h[j] = (unsigned short)(p & 0xffffu); l[j] = (unsigned short)(p >> 16);
      }
      *(u16x4*)&Bh[row][c4] = h; *(u16x4*)&Bl[row][c4] = l;
    }
    __syncthreads();
    if (k0 + 64 < ND) {
#pragma unroll
      for (int r = 0; r < 8; ++r) {
        vreg[r] = *(const f32x4*)(V + (size_t)(row0 + srow + r * 16) * ND + k0 + 64 + c4);
        wreg[r] = *(const f32x4*)(W + (size_t)(col0 + srow + r * 16) * ND + k0 + 64 + c4);
      }
    }
#pragma unroll
    for (int kk = 0; kk < 2; ++kk) {
      int kof = kk * 32 + g * 8;
      bf16x8 ah[4], al[4], bh[4], bl[4];
#pragma unroll
      for (int i = 0; i < 4; ++i) {
        int ra = wr + i * 16 + l15;
        ah[i] = *(const bf16x8*)&Ah[ra][kof];
        al[i] = *(const bf16x8*)&Al[ra][kof];
        int rb = wc + i * 16 + l15;
        bh[i] = *(const bf16x8*)&Bh[rb][kof];
        bl[i] = *(const bf16x8*)&Bl[rb][kof];
      }
#pragma unroll
      for (int i = 0; i < 4; ++i)
#pragma unroll
        for (int j = 0; j < 4; ++j) {
          acc[i][j] = mfma_bf(ah[i], bh[j], acc[i][j]);
          acc[i][j] = mfma_bf(ah[i], bl[j], acc[i][j]);
          acc[i][j] = mfma_bf(al[i], bh[j], acc[i][j]);
        }
    }
  }
  // epilogue: f32 C-tile in LDS (pitch 132), then fp16 coalesced writes (256B runs)
  __syncthreads();
  float* CT = (float*)SMEM;                    // 128 x 132 f32 = 67584 B
#pragma unroll
  for (int j = 0; j < 4; ++j) {
    int col_l = wc + j * 16 + l15;
    float bj = bias[col0 + col_l];
#pragma unroll
    for (int i = 0; i < 4; ++i) {
      int rb_l = wr + i * 16 + g * 4;
#pragma unroll
      for (int r = 0; r < 4; ++r) CT[(rb_l + r) * 132 + col_l] = acc[i][j][r] + bj;
    }
  }
  __syncthreads();
#pragma unroll
  for (int it = 0; it < 16; ++it) {
    int idx = it * 256 + t;                  // 4096 chunks of 4
    int row = idx >> 5, cc = (idx & 31) * 4;
    f32x4 x = *(const f32x4*)&CT[row * 132 + cc];
    u16x4 h;
#pragma unroll
    for (int j = 0; j < 4; ++j) h[j] = f2h(x[j]);
    *(u16x4*)(kp + (size_t)(row0 + row) * 2048 + col0 + cc) = h;
  }
}

// ------- kernel 2: scores = Q @ keys^T in fp16 single-MFMA via global_load_lds + swizzle -------
// + fused block softmax: e = exp(s - m_blk) fp16 [b][q][v] -> ebase; partial (m,l).
__global__ __launch_bounds__(256, 3) void k_scores(const unsigned short* __restrict__ qh,
                                                   const unsigned short* kp,
                                                   unsigned short* ebase,
                                                   float2* __restrict__ partials) {
  int bid = blockIdx.x;
  int swz = (bid & 7) * 256 + (bid >> 3);
  int b = swz >> 6, rr2 = swz & 63, vt = rr2 >> 3, qt = rr2 & 7;
  int t = threadIdx.x, lane = t & 63, w = t >> 6, g = lane >> 4, l15 = lane & 15;
  int wr = (w >> 1) * 64, wc = (w & 1) * 64;
  __shared__ __align__(16) unsigned char SMEM[36864];
  unsigned short* lds = (unsigned short*)SMEM;   // A @ u16 0, B @ u16 8192
  f32x4 acc[4][4] = {};
  const size_t qrow = (size_t)(b * NTQ + qt * 128);
  const size_t krow = (size_t)(b * NTV + vt * 128);
  int grow = lane >> 3;          // row sub-index within chunk
  int gcg = lane & 7;            // col granule (16B) within 128B row

  for (int k0 = 0; k0 < ND; k0 += 64) {
    __syncthreads();
#pragma unroll
    for (int i = 0; i < 4; ++i) {
      int c = i * 4 + w;                       // 0..15
      int row = c * 8 + grow;                  // 0..127
      int scg = gcg ^ (row & 7);               // inverse-swizzled SOURCE column-group
      gload16(qh + (qrow + row) * 512 + k0 + scg * 8, lds + c * 512);
      gload16(kp + (krow + row) * 2048 + k0 + scg * 8, lds + 8192 + c * 512);
    }
    __syncthreads();                           // drains vmcnt -> tiles ready
#pragma unroll
    for (int kk = 0; kk < 2; ++kk) {
      f16x8 af[4], bfr[4];
#pragma unroll
      for (int i = 0; i < 4; ++i) {
        int ra = wr + i * 16 + l15;
        int go = ((kk * 4 + g) ^ (ra & 7)) * 8;   // swizzled read column offset (u16)
        af[i] = *(const f16x8*)(lds + ra * 64 + go);
        int rb = wc + i * 16 + l15;
        int go2 = ((kk * 4 + g) ^ (rb & 7)) * 8;
        bfr[i] = *(const f16x8*)(lds + 8192 + rb * 64 + go2);
      }
#pragma unroll
      for (int i = 0; i < 4; ++i)
#pragma unroll
        for (int j = 0; j < 4; ++j) acc[i][j] = mfma_h(af[i], bfr[j], acc[i][j]);
    }
  }
  // ---- fused block softmax: m over this block's 128 v per q; e tile fp16 [q][v]; partial (m,l) ----
  __syncthreads();
  auto E2 = (unsigned short(*)[136])(SMEM);     // [128 q][136] u16 = 34816 B
  float* Lm = (float*)(SMEM + 34816);           // [128][2] f32
  float* Ls = (float*)(SMEM + 35840);
#pragma unroll
  for (int i = 0; i < 4; ++i)
#pragma unroll
    for (int r = 0; r < 4; ++r) {
      float m = fmaxf(fmaxf(acc[i][0][r], acc[i][1][r]), fmaxf(acc[i][2][r], acc[i][3][r]));
#pragma unroll
      for (int msk = 1; msk < 16; msk <<= 1) m = fmaxf(m, __shfl_xor(m, msk));
      if (l15 == 0) Lm[(wr + i * 16 + g * 4 + r) * 2 + (w & 1)] = m;
    }
  __syncthreads();
#pragma unroll
  for (int i = 0; i < 4; ++i)
#pragma unroll
    for (int r = 0; r < 4; ++r) {
      int ql = wr + i * 16 + g * 4 + r;
      float mf = fmaxf(Lm[ql * 2], Lm[ql * 2 + 1]);
      float s = 0.f;
#pragma unroll
      for (int j = 0; j < 4; ++j) {
        float e = __expf(acc[i][j][r] - mf);
        s += e;
        E2[ql][wc + j * 16 + l15] = f2h(e);     // q-major store
      }
#pragma unroll
      for (int msk = 1; msk < 16; msk <<= 1) s += __shfl_xor(s, msk);
      if (l15 == 0) Ls[ql * 2 + (w & 1)] = s;
    }
  __syncthreads();
  if (t < 128) {
    float mf = fmaxf(Lm[t * 2], Lm[t * 2 + 1]);
    float lf = Ls[t * 2] + Ls[t * 2 + 1];
    partials[(((size_t)(b * 8 + vt)) << 10) + qt * 128 + t] = make_float2(mf, lf);
  }
  // e rows q (128), 256B runs at v-column offset vt*128
#pragma unroll
  for (int it = 0; it < 8; ++it) {
    int idx = it * 256 + t;
    int row = idx >> 4, ch = idx & 15;
    *(u16x8*)(ebase + (size_t)(b * 1024 + qt * 128 + row) * 2048 + 1024 + vt * 128 + ch * 8) =
        *(const u16x8*)&E2[row][ch * 8];
  }
}

// ------- kernel 3: combine 8 partials per (b,q) -> global (M, 1/L) -------
__global__ __launch_bounds__(256) void k_combine(const float2* __restrict__ partials,
                                                 float2* __restrict__ stats) {
  int idx = blockIdx.x * 256 + threadIdx.x;   // 32768
  int b = idx >> 10, q = idx & 1023;
  float2 p[8];
  float M = -3.0e38f;
#pragma unroll
  for (int vt = 0; vt < 8; ++vt) {
    p[vt] = partials[(((size_t)(b * 8 + vt)) << 10) + q];
    M = fmaxf(M, p[vt].x);
  }
  float L = 0.f;
#pragma unroll
  for (int vt = 0; vt < 8; ++vt) L += p[vt].y * __expf(p[vt].x - M);
  stats[idx] = make_float2(M, 1.0f / L);
}

// ------- kernel 4: context = alpha @ V ; 128q x 128d fp16 tile GEMM over K=v -------
__global__ __launch_bounds__(256, 3) void k_pv(const unsigned short* __restrict__ ebase,
                                               const unsigned short* __restrict__ Vt,
                                               const float2* __restrict__ stats,
                                               const float2* __restrict__ partials,
                                               float* __restrict__ out1) {
  int bid = blockIdx.x;
  int swz = (bid & 7) * 128 + (bid >> 3);
  int b = swz >> 5, qt = (swz >> 2) & 7, dt = swz & 3;
  int t = threadIdx.x, lane = t & 63, w = t >> 6;
  int l15 = lane & 15, g = lane >> 4;
  int wr = (w >> 1) * 64, wc = (w & 1) * 64;
  int q0 = qt * 128, d0 = dt * 128;
  __shared__ __align__(16) unsigned char SMEM[36864];
  auto Ae = (unsigned short(*)[72])(SMEM);           // [128 q][72]
  auto Bv = (unsigned short(*)[72])(SMEM + 18432);   // [128 d][72]
  f32x4 acc[4][4] = {};

  int srow = t >> 3, c8 = (t & 7) * 8;
  float M4[4], iL4[4];
#pragma unroll
  for (int k = 0; k < 4; ++k) {
    float2 st = stats[b * NTQ + q0 + srow + 32 * k];
    M4[k] = st.x; iL4[k] = st.y;
  }
  u16x8 ereg[4], vreg[4];
#pragma unroll
  for (int k = 0; k < 4; ++k) {
    ereg[k] = *(const u16x8*)(ebase + (size_t)(b * 1024 + q0 + srow + 32 * k) * 2048 + 1024 + c8);
    vreg[k] = *(const u16x8*)(Vt + ((size_t)b * ND + d0 + srow + 32 * k) * NTV + c8);
  }
  float sck[4];
  for (int v0 = 0; v0 < NTV; v0 += 64) {
    if ((v0 & 127) == 0) {
      int vt128 = v0 >> 7;
#pragma unroll
      for (int k = 0; k < 4; ++k) {
        float2 p = partials[(((size_t)(b * 8 + vt128)) << 10) + q0 + srow + 32 * k];
        sck[k] = __expf(p.x - M4[k]) * iL4[k];
      }
    }
    __syncthreads();
#pragma unroll
    for (int k = 0; k < 4; ++k) {
      int row = srow + 32 * k;
      u16x8 a;
#pragma unroll
      for (int m = 0; m < 8; ++m) a[m] = f2h(h2f(ereg[k][m]) * sck[k]);
      *(u16x8*)&Ae[row][c8] = a;
      *(u16x8*)&Bv[row][c8] = vreg[k];
    }
    if (v0 + 64 < NTV) {
#pragma unroll
      for (int k = 0; k < 4; ++k) {
        ereg[k] = *(const u16x8*)(ebase + (size_t)(b * 1024 + q0 + srow + 32 * k) * 2048 + 1024 + v0 + 64 + c8);
        vreg[k] = *(const u16x8*)(Vt + ((size_t)b * ND + d0 + srow + 32 * k) * NTV + v0 + 64 + c8);
      }
    }
    __syncthreads();
#pragma unroll
    for (int kk = 0; kk < 2; ++kk) {
      int kof = kk * 32 + g * 8;
      f16x8 af[4], bfr[4];
#pragma unroll
      for (int i = 0; i < 4; ++i) af[i] = *(const f16x8*)&Ae[wr + i * 16 + l15][kof];
#pragma unroll
      for (int j = 0; j < 4; ++j) bfr[j] = *(const f16x8*)&Bv[wc + j * 16 + l15][kof];
#pragma unroll
      for (int i = 0; i < 4; ++i)
#pragma unroll
        for (int j = 0; j < 4; ++j) acc[i][j] = mfma_h(af[i], bfr[j], acc[i][j]);
    }
  }
  float* CT = (float*)SMEM;
#pragma unroll
  for (int h = 0; h < 2; ++h) {
    __syncthreads();
    if ((w >> 1) == h) {
#pragma unroll
      for (int i = 0; i < 4; ++i)
#pragma unroll
        for (int j = 0; j < 4; ++j) {
          int ql = i * 16 + g * 4;
          int dl = wc + j * 16 + l15;
#pragma unroll
          for (int r = 0; r < 4; ++r) CT[(ql + r) * 132 + dl] = acc[i][j][r];
        }
    }
    __syncthreads();
#pragma unroll
    for (int it = 0; it < 8; ++it) {
      int idx = it * 256 + t;
      int row = idx >> 5, c4 = idx & 31;
      *(f32x4*)(out1 + (size_t)(b * NTQ + q0 + h * 64 + row) * 1024 + d0 + c4 * 4) =
          *(const f32x4*)&CT[row * 132 + c4 * 4];
    }
  }
}

// ------- kernel 5: alpha = e*sc -> out2 (via swizzled LDS transpose) + fused Q-concat -------
__global__ __launch_bounds__(256) void k_alpha(const unsigned short* ebase,
                                               const float* __restrict__ Q,
                                               const float2* __restrict__ stats,
                                               const float2* __restrict__ partials,
                                               float* out2,
                                               float* out1) {
  int bid = blockIdx.x;                       // 512
  int swz = (bid & 7) * 64 + (bid >> 3);
  int b = swz >> 4, qc = swz & 15;
  int q0 = qc * 64;
  int t = threadIdx.x;
  __shared__ float T[128][68];
  int row = t >> 4, ch = t & 15;
  float M4[4], iL4[4];
#pragma unroll
  for (int k = 0; k < 4; ++k) {
    float2 st = stats[b * NTQ + q0 + row + 16 * k];
    M4[k] = st.x; iL4[k] = st.y;
  }
  for (int vt = 0; vt < 8; ++vt) {
    __syncthreads();
#pragma unroll
    for (int k = 0; k < 4; ++k) {
      int r = row + 16 * k;
      float2 p = partials[(((size_t)(b * 8 + vt)) << 10) + q0 + r];
      float sc = __expf(p.x - M4[k]) * iL4[k];
      u16x8 ev = *(const u16x8*)(ebase + (size_t)(b * 1024 + q0 + r) * 2048 + 1024 + vt * 128 + ch * 8);
#pragma unroll
      for (int m = 0; m < 8; ++m) {
        int v = ch * 8 + m;
        T[v][r ^ (((v >> 3) & 7) << 3)] = h2f(ev[m]) * sc;
      }
    }
    __syncthreads();
#pragma unroll
    for (int it = 0; it < 8; ++it) {
      int idx = it * 256 + t;
      int vr = idx >> 4, c4 = idx & 15;
      int cs = (c4 * 4) ^ (((vr >> 3) & 7) << 3);
      *(f32x4*)(out2 + ((size_t)(b * 1024) + vt * 128 + vr) * 1024 + q0 + c4 * 4) =
          *(const f32x4*)&T[vr][cs];
    }
  }
  __syncthreads();
#pragma unroll
  for (int k = 0; k < 32; ++k) {
    int idx = k * 256 + t;
    int r = idx >> 7, c4 = idx & 127;
    *(f32x4*)(out1 + (size_t)(b * 1024 + q0 + r) * 1024 + 512 + c4 * 4) =
        *(const f32x4*)(Q + (size_t)(b * 1024 + q0 + r) * 512 + c4 * 4);
  }
}

extern "C" void kernel_launch(void* const* d_in, const int* in_sizes, int n_in,
                              void* d_out, int out_size, void* d_ws, size_t ws_size,
                              hipStream_t stream) {
  const float* Q    = (const float*)d_in[0];
  const float* V    = (const float*)d_in[1];
  const float* W    = (const float*)d_in[2];
  const float* bias = (const float*)d_in[3];

  float* out1 = (float*)d_out;                                   // context_cat [B,TQ,2D]
  float* out2 = (float*)d_out + (size_t)NB * NTQ * (2 * ND);     // alignment_t [B,TV,TQ]

  unsigned short* Vt = (unsigned short*)d_ws;                    // fp16 [B,D,TV]  32MB
  float2* stats    = (float2*)((char*)d_ws + 33554432);          // 256KB
  float2* partials = (float2*)((char*)d_ws + 33554432 + 262144); // 2MB

  // keys fp16 plane: out1 row (b,v) u16 [0..511]
  unsigned short* kp = (unsigned short*)out1;
  // e fp16 [b][q][v]: out1 row (b,q) u16 [1024..2047]
  unsigned short* ebase = (unsigned short*)out1;
  // q fp16 plane: out2 region start (dead until k_alpha)
  unsigned short* qh = (unsigned short*)out2;

  k_vt<<<dim3(16, 8, 32), 256, 0, stream>>>(V, Vt);
  k_qhalf<<<4096, 256, 0, stream>>>(Q, qh);
  k_keys<<<1024, 256, 0, stream>>>(V, W, bias, kp);
  k_scores<<<2048, 256, 0, stream>>>(qh, kp, ebase, partials);
  k_combine<<<128, 256, 0, stream>>>(partials, stats);
  k_pv<<<1024, 256, 0, stream>>>(ebase, Vt, stats, partials, out1);
  k_alpha<<<512, 256, 0, stream>>>(ebase, Q, stats, partials, out2, out1);
}